// Round 4
// baseline (88.087 us; speedup 1.0000x reference)
//
#include <hip/hip_runtime.h>
#include <math.h>

#define NH 128   // hidden
#define NP 7     // particles
#define ND 16    // per-particle dim
#define NF 112   // NP*ND
#define NB 128   // batch

#define CC 2.8853900817779268f   // 2*log2(e): exp2(CC*s) = e^{2s}

typedef float f2 __attribute__((ext_vector_type(2)));

__device__ __forceinline__ float rcpf(float x) { return __builtin_amdgcn_rcpf(x); }

#define GLD(i, j) (*(const f2*)&psh[((i) * 7 + (j)) * NH + (lane << 1)])

// Pair (a,b) at positions 5,6 under prefix-exp E4:
//   contribution = +/- (ea-eb)/((1+ea)(1+eb)), compile-time sign via fma neg-modifier
#define PAIRP(E4v, A5, A6, B5, B6) do {            \
    f2 t = (A5) * (B6);                            \
    f2 u = (B5) * (A6);                            \
    f2 ea = (E4v) * t;                             \
    f2 eb = (E4v) * u;                             \
    f2 num = ea - eb;                              \
    f2 den = (ea + 1.0f) * (eb + 1.0f);            \
    f2 rd; rd.x = rcpf(den.x); rd.y = rcpf(den.y); \
    accT.x = fmaf(num.x, rd.x, accT.x);            \
    accT.y = fmaf(num.y, rd.y, accT.y);            \
  } while (0)

#define PAIRM(E4v, A5, A6, B5, B6) do {            \
    f2 t = (A5) * (B6);                            \
    f2 u = (B5) * (A6);                            \
    f2 ea = (E4v) * t;                             \
    f2 eb = (E4v) * u;                             \
    f2 num = ea - eb;                              \
    f2 den = (ea + 1.0f) * (eb + 1.0f);            \
    f2 rd; rd.x = rcpf(den.x); rd.y = rcpf(den.y); \
    accT.x = fmaf(-num.x, rd.x, accT.x);           \
    accT.y = fmaf(-num.y, rd.y, accT.y);           \
  } while (0)

// position-3 element with +sg2 relative sign; trio P<Q<R at positions 4,5,6
#define T3P(G3, M4A, M4B, M4C, A5, A6, B5, B6, C5, C6) do { \
    f2 E3 = E2 * (G3);                                      \
    PAIRP(E3 * (M4A), B5, B6, C5, C6);                      \
    PAIRM(E3 * (M4B), A5, A6, C5, C6);                      \
    PAIRP(E3 * (M4C), A5, A6, B5, B6);                      \
  } while (0)

// position-3 element with -sg2 relative sign
#define T3M(G3, M4A, M4B, M4C, A5, A6, B5, B6, C5, C6) do { \
    f2 E3 = E2 * (G3);                                      \
    PAIRM(E3 * (M4A), B5, B6, C5, C6);                      \
    PAIRP(E3 * (M4B), A5, A6, C5, C6);                      \
    PAIRM(E3 * (M4C), A5, A6, B5, B6);                      \
  } while (0)

extern "C" __global__ void __launch_bounds__(512, 8)
antisym_leaf_kernel(const float* __restrict__ x0, const float* __restrict__ x1,
                    const float* __restrict__ W0, const float* __restrict__ b0,
                    const float* __restrict__ V0,
                    const float* __restrict__ W1, const float* __restrict__ b1,
                    const float* __restrict__ V1,
                    float* __restrict__ ws) {
  __shared__ float psh[49 * NH];   // P[i][j][h] = exp(2*G[i][j][h])
  __shared__ float xs[NF];
  __shared__ float red[8];

  const int tid  = threadIdx.x;
  const int bid  = blockIdx.x;          // [0, 1024)
  const int leaf = bid >> 9;
  const int qtr  = (bid >> 7) & 3;
  const int b    = bid & 127;

  const float* xL = leaf ? x1 : x0;
  const float* WL = leaf ? W1 : W0;
  const float* bL = leaf ? b1 : b0;
  const float* vL = leaf ? V1 : V0;

  // ---- Phase A: stage x row, build P[i][j][h] = exp(2*x_j . W_i[:,h]) in LDS ----
  if (tid < NF) xs[tid] = xL[b * NF + tid];
  __syncthreads();

  for (int idx = tid; idx < 49 * NH; idx += 512) {
    int h  = idx & (NH - 1);
    int ij = idx >> 7;          // 0..48
    int i  = ij / 7;
    int j  = ij - 7 * i;
    const float* wp = WL + i * ND * NH + h;   // coalesced over h
    const float* xp = xs + j * ND;
    float v = 0.f;
#pragma unroll
    for (int k = 0; k < ND; ++k) v = fmaf(xp[k], wp[k * NH], v);
    psh[idx] = __builtin_amdgcn_exp2f(v * CC);
  }
  __syncthreads();

  // ---- Phase B: tree-enumerate all 5040 permutations via prefix-exp products ----
  const int lane = tid & 63;
  const int wid  = tid >> 6;            // 0..7
  const int slot = (qtr << 3) | wid;    // 0..31

  f2 bias2 = ((const f2*)bL)[lane];
  f2 V2    = ((const f2*)vL)[lane];
  f2 Eb;
  Eb.x = __builtin_amdgcn_exp2f(bias2.x * CC);
  Eb.y = __builtin_amdgcn_exp2f(bias2.y * CC);
  f2 acc = {0.f, 0.f};

  int m = 0;  // linear index over the 210 (t0,t1,t2) triples
#pragma unroll 1
  for (int t0 = 0; t0 < 7; ++t0) {
    float sg0 = (t0 & 1) ? -1.f : 1.f;
    f2 E0 = Eb * GLD(0, t0);
    int c1 = 0;
#pragma unroll 1
    for (int t1 = 0; t1 < 7; ++t1) {
      if (t1 == t0) continue;
      float sg1 = (c1 & 1) ? -sg0 : sg0; ++c1;
      f2 E1 = E0 * GLD(1, t1);
      int c2 = 0;
#pragma unroll 1
      for (int t2 = 0; t2 < 7; ++t2) {
        if (t2 == t0 || t2 == t1) continue;
        float sg2 = (c2 & 1) ? -sg1 : sg1; ++c2;
        if ((m++ & 31) != slot) continue;   // round-robin triples over 32 wave-slots
        int rm = 0x7F & ~((1 << t0) | (1 << t1) | (1 << t2));
        int e0 = __ffs(rm) - 1; rm &= rm - 1;
        int e1 = __ffs(rm) - 1; rm &= rm - 1;
        int e2i = __ffs(rm) - 1; rm &= rm - 1;
        int e3 = __ffs(rm) - 1;

        // one 17-deep ds_read batch per trio -> single lgkmcnt wait
        f2 E2  = E1 * GLD(2, t2);
        f2 g30 = GLD(3, e0), g31 = GLD(3, e1), g32 = GLD(3, e2i), g33 = GLD(3, e3);
        f2 m40 = GLD(4, e0), m41 = GLD(4, e1), m42 = GLD(4, e2i), m43 = GLD(4, e3);
        f2 m50 = GLD(5, e0), m51 = GLD(5, e1), m52 = GLD(5, e2i), m53 = GLD(5, e3);
        f2 m60 = GLD(6, e0), m61 = GLD(6, e1), m62 = GLD(6, e2i), m63 = GLD(6, e3);

        f2 accT = {0.f, 0.f};
        T3P(g30, m41, m42, m43, m51, m61, m52, m62, m53, m63);
        T3M(g31, m40, m42, m43, m50, m60, m52, m62, m53, m63);
        T3P(g32, m40, m41, m43, m50, m60, m51, m61, m53, m63);
        T3M(g33, m40, m41, m42, m50, m60, m51, m61, m52, m62);
        acc.x = fmaf(sg2, accT.x, acc.x);
        acc.y = fmaf(sg2, accT.y, acc.y);
      }
    }
  }

  // ---- Reduce: partial psi = sum_h V[h] * acc[h] (factor 2 in finalize) ----
  float part = V2.x * acc.x + V2.y * acc.y;
#pragma unroll
  for (int off = 32; off > 0; off >>= 1) part += __shfl_xor(part, off, 64);
  if (lane == 0) red[wid] = part;
  __syncthreads();
  if (tid == 0) {
    float tot = 0.f;
#pragma unroll
    for (int w = 0; w < 8; ++w) tot += red[w];
    ws[leaf * 512 + qtr * 128 + b] = tot;
  }
}

extern "C" __global__ void finalize_kernel(const float* __restrict__ ws,
                                           float* __restrict__ out) {
  int t = threadIdx.x;
  if (t < NB) {
    float p0 = 2.0f * (ws[t] + ws[128 + t] + ws[256 + t] + ws[384 + t]);
    float p1 = 2.0f * (ws[512 + t] + ws[640 + t] + ws[768 + t] + ws[896 + t]);
    float s0 = (p0 > 0.f) ? 1.f : ((p0 < 0.f) ? -1.f : 0.f);
    float s1 = (p1 > 0.f) ? 1.f : ((p1 < 0.f) ? -1.f : 0.f);
    out[t]      = s0 * s1;                            // sign
    out[NB + t] = logf(fabsf(p0)) + logf(fabsf(p1));  // logabs
  }
}

extern "C" void kernel_launch(void* const* d_in, const int* in_sizes, int n_in,
                              void* d_out, int out_size, void* d_ws, size_t ws_size,
                              hipStream_t stream) {
  const float* x0 = (const float*)d_in[0];
  const float* x1 = (const float*)d_in[1];
  const float* W0 = (const float*)d_in[2];
  const float* b0 = (const float*)d_in[3];
  const float* V0 = (const float*)d_in[4];
  // d_in[5] = c0: cancels under antisymmetrization (sum of signs == 0)
  const float* W1 = (const float*)d_in[6];
  const float* b1 = (const float*)d_in[7];
  const float* V1 = (const float*)d_in[8];
  // d_in[9] = c1: cancels

  float* ws  = (float*)d_ws;      // 1024 floats: psi partials [leaf][quarter][b]
  float* out = (float*)d_out;     // 256 floats: sign[128], logabs[128]

  antisym_leaf_kernel<<<1024, 512, 0, stream>>>(x0, x1, W0, b0, V0, W1, b1, V1, ws);
  finalize_kernel<<<1, NB, 0, stream>>>(ws, out);
}

// Round 5
// 82.983 us; speedup vs baseline: 1.0615x; 1.0615x over previous
//
#include <hip/hip_runtime.h>
#include <math.h>

#define NH 128   // hidden
#define NP 7     // particles
#define ND 16    // per-particle dim
#define NF 112   // NP*ND
#define NB 128   // batch

#define CC 2.8853900817779268f   // 2*log2(e): exp2(CC*s) = e^{2s}

typedef float f2 __attribute__((ext_vector_type(2)));

__device__ __forceinline__ float rcpf(float x) { return __builtin_amdgcn_rcpf(x); }

#define GLD(i, j) (*(const f2*)&psh[((i) * 7 + (j)) * NH + (lane << 1)])

// Pair (a,b) at positions 5,6 under prefix-exp E4:
//   contribution = +/- (ea-eb)/((1+ea)(1+eb)), compile-time sign via fma neg-modifier
#define PAIRP(E4v, A5, A6, B5, B6) do {            \
    f2 t = (A5) * (B6);                            \
    f2 u = (B5) * (A6);                            \
    f2 ea = (E4v) * t;                             \
    f2 eb = (E4v) * u;                             \
    f2 num = ea - eb;                              \
    f2 den = (ea + 1.0f) * (eb + 1.0f);            \
    f2 rd; rd.x = rcpf(den.x); rd.y = rcpf(den.y); \
    accT.x = fmaf(num.x, rd.x, accT.x);            \
    accT.y = fmaf(num.y, rd.y, accT.y);            \
  } while (0)

#define PAIRM(E4v, A5, A6, B5, B6) do {            \
    f2 t = (A5) * (B6);                            \
    f2 u = (B5) * (A6);                            \
    f2 ea = (E4v) * t;                             \
    f2 eb = (E4v) * u;                             \
    f2 num = ea - eb;                              \
    f2 den = (ea + 1.0f) * (eb + 1.0f);            \
    f2 rd; rd.x = rcpf(den.x); rd.y = rcpf(den.y); \
    accT.x = fmaf(-num.x, rd.x, accT.x);           \
    accT.y = fmaf(-num.y, rd.y, accT.y);           \
  } while (0)

// position-3 element with +sg2 relative sign; trio P<Q<R at positions 4,5,6
#define T3P(G3, M4A, M4B, M4C, A5, A6, B5, B6, C5, C6) do { \
    f2 E3 = E2 * (G3);                                      \
    PAIRP(E3 * (M4A), B5, B6, C5, C6);                      \
    PAIRM(E3 * (M4B), A5, A6, C5, C6);                      \
    PAIRP(E3 * (M4C), A5, A6, B5, B6);                      \
  } while (0)

// position-3 element with -sg2 relative sign
#define T3M(G3, M4A, M4B, M4C, A5, A6, B5, B6, C5, C6) do { \
    f2 E3 = E2 * (G3);                                      \
    PAIRM(E3 * (M4A), B5, B6, C5, C6);                      \
    PAIRP(E3 * (M4B), A5, A6, C5, C6);                      \
    PAIRM(E3 * (M4C), A5, A6, B5, B6);                      \
  } while (0)

extern "C" __global__ void __launch_bounds__(512, 4)
antisym_leaf_kernel(const float* __restrict__ x0, const float* __restrict__ x1,
                    const float* __restrict__ W0, const float* __restrict__ b0,
                    const float* __restrict__ V0,
                    const float* __restrict__ W1, const float* __restrict__ b1,
                    const float* __restrict__ V1,
                    float* __restrict__ ws) {
  __shared__ float psh[49 * NH];   // P[i][j][h] = exp(2*G[i][j][h])
  __shared__ float xs[NF];
  __shared__ float red[8];

  const int tid  = threadIdx.x;
  const int bid  = blockIdx.x;          // [0, 1024)
  const int leaf = bid >> 9;
  const int qtr  = (bid >> 7) & 3;
  const int b    = bid & 127;

  const float* xL = leaf ? x1 : x0;
  const float* WL = leaf ? W1 : W0;
  const float* bL = leaf ? b1 : b0;
  const float* vL = leaf ? V1 : V0;

  // ---- Phase A: stage x row, build P[i][j][h] = exp(2*x_j . W_i[:,h]) in LDS ----
  if (tid < NF) xs[tid] = xL[b * NF + tid];
  __syncthreads();

  for (int idx = tid; idx < 49 * NH; idx += 512) {
    int h  = idx & (NH - 1);
    int ij = idx >> 7;          // 0..48
    int i  = ij / 7;
    int j  = ij - 7 * i;
    const float* wp = WL + i * ND * NH + h;   // coalesced over h
    const float* xp = xs + j * ND;
    float v = 0.f;
#pragma unroll
    for (int k = 0; k < ND; ++k) v = fmaf(xp[k], wp[k * NH], v);
    psh[idx] = __builtin_amdgcn_exp2f(v * CC);
  }
  __syncthreads();

  // ---- Phase B: tree-enumerate all 5040 permutations via prefix-exp products ----
  const int lane = tid & 63;
  const int wid  = tid >> 6;            // 0..7
  const int slot = (qtr << 3) | wid;    // 0..31

  f2 bias2 = ((const f2*)bL)[lane];
  f2 V2    = ((const f2*)vL)[lane];
  f2 Eb;
  Eb.x = __builtin_amdgcn_exp2f(bias2.x * CC);
  Eb.y = __builtin_amdgcn_exp2f(bias2.y * CC);
  f2 acc = {0.f, 0.f};

  int m = 0;  // linear index over the 210 (t0,t1,t2) triples
#pragma unroll 1
  for (int t0 = 0; t0 < 7; ++t0) {
    float sg0 = (t0 & 1) ? -1.f : 1.f;
    f2 E0 = Eb * GLD(0, t0);
    int c1 = 0;
#pragma unroll 1
    for (int t1 = 0; t1 < 7; ++t1) {
      if (t1 == t0) continue;
      float sg1 = (c1 & 1) ? -sg0 : sg0; ++c1;
      f2 E1 = E0 * GLD(1, t1);
      int c2 = 0;
#pragma unroll 1
      for (int t2 = 0; t2 < 7; ++t2) {
        if (t2 == t0 || t2 == t1) continue;
        float sg2 = (c2 & 1) ? -sg1 : sg1; ++c2;
        if ((m++ & 31) != slot) continue;   // round-robin triples over 32 wave-slots
        int rm = 0x7F & ~((1 << t0) | (1 << t1) | (1 << t2));
        int e0 = __ffs(rm) - 1; rm &= rm - 1;
        int e1 = __ffs(rm) - 1; rm &= rm - 1;
        int e2i = __ffs(rm) - 1; rm &= rm - 1;
        int e3 = __ffs(rm) - 1;

        // one 17-deep ds_read batch per trio -> single lgkmcnt wait
        f2 E2  = E1 * GLD(2, t2);
        f2 g30 = GLD(3, e0), g31 = GLD(3, e1), g32 = GLD(3, e2i), g33 = GLD(3, e3);
        f2 m40 = GLD(4, e0), m41 = GLD(4, e1), m42 = GLD(4, e2i), m43 = GLD(4, e3);
        f2 m50 = GLD(5, e0), m51 = GLD(5, e1), m52 = GLD(5, e2i), m53 = GLD(5, e3);
        f2 m60 = GLD(6, e0), m61 = GLD(6, e1), m62 = GLD(6, e2i), m63 = GLD(6, e3);

        f2 accT = {0.f, 0.f};
        T3P(g30, m41, m42, m43, m51, m61, m52, m62, m53, m63);
        T3M(g31, m40, m42, m43, m50, m60, m52, m62, m53, m63);
        T3P(g32, m40, m41, m43, m50, m60, m51, m61, m53, m63);
        T3M(g33, m40, m41, m42, m50, m60, m51, m61, m52, m62);
        acc.x = fmaf(sg2, accT.x, acc.x);
        acc.y = fmaf(sg2, accT.y, acc.y);
      }
    }
  }

  // ---- Reduce: partial psi = sum_h V[h] * acc[h] (factor 2 in finalize) ----
  float part = V2.x * acc.x + V2.y * acc.y;
#pragma unroll
  for (int off = 32; off > 0; off >>= 1) part += __shfl_xor(part, off, 64);
  if (lane == 0) red[wid] = part;
  __syncthreads();
  if (tid == 0) {
    float tot = 0.f;
#pragma unroll
    for (int w = 0; w < 8; ++w) tot += red[w];
    ws[leaf * 512 + qtr * 128 + b] = tot;
  }
}

extern "C" __global__ void finalize_kernel(const float* __restrict__ ws,
                                           float* __restrict__ out) {
  int t = threadIdx.x;
  if (t < NB) {
    float p0 = 2.0f * (ws[t] + ws[128 + t] + ws[256 + t] + ws[384 + t]);
    float p1 = 2.0f * (ws[512 + t] + ws[640 + t] + ws[768 + t] + ws[896 + t]);
    float s0 = (p0 > 0.f) ? 1.f : ((p0 < 0.f) ? -1.f : 0.f);
    float s1 = (p1 > 0.f) ? 1.f : ((p1 < 0.f) ? -1.f : 0.f);
    out[t]      = s0 * s1;                            // sign
    out[NB + t] = logf(fabsf(p0)) + logf(fabsf(p1));  // logabs
  }
}

extern "C" void kernel_launch(void* const* d_in, const int* in_sizes, int n_in,
                              void* d_out, int out_size, void* d_ws, size_t ws_size,
                              hipStream_t stream) {
  const float* x0 = (const float*)d_in[0];
  const float* x1 = (const float*)d_in[1];
  const float* W0 = (const float*)d_in[2];
  const float* b0 = (const float*)d_in[3];
  const float* V0 = (const float*)d_in[4];
  // d_in[5] = c0: cancels under antisymmetrization (sum of signs == 0)
  const float* W1 = (const float*)d_in[6];
  const float* b1 = (const float*)d_in[7];
  const float* V1 = (const float*)d_in[8];
  // d_in[9] = c1: cancels

  float* ws  = (float*)d_ws;      // 1024 floats: psi partials [leaf][quarter][b]
  float* out = (float*)d_out;     // 256 floats: sign[128], logabs[128]

  antisym_leaf_kernel<<<1024, 512, 0, stream>>>(x0, x1, W0, b0, V0, W1, b1, V1, ws);
  finalize_kernel<<<1, NB, 0, stream>>>(ws, out);
}

// Round 6
// 30.537 us; speedup vs baseline: 2.8846x; 2.7175x over previous
//
#include <hip/hip_runtime.h>
#include <math.h>

#define NH 128   // hidden
#define ND 16    // per-particle dim
#define NF 112   // 7*ND
#define NB 128   // batch

#define CC 2.8853900817779268f   // 2*log2(e): exp2(CC*s) = e^{2s}

typedef float f2 __attribute__((ext_vector_type(2)));

__device__ __forceinline__ float rcpf(float x) { return __builtin_amdgcn_rcpf(x); }

#define GLD(i, j) (*(const f2*)&psh[((i) * 7 + (j)) * NH + (lane << 1)])

// Pair (a,b) at positions 5,6 under prefix-exp E4:
//   +/- (ea-eb)/((1+ea)(1+eb)), sign compile-time via fma neg-modifier; accum into accG
#define PAIRP(E4v, A5, A6, B5, B6) do {            \
    f2 ea = (E4v) * ((A5) * (B6));                 \
    f2 eb = (E4v) * ((B5) * (A6));                 \
    f2 num = ea - eb;                              \
    f2 den = (ea + 1.0f) * (eb + 1.0f);            \
    f2 rd; rd.x = rcpf(den.x); rd.y = rcpf(den.y); \
    accG.x = fmaf(num.x, rd.x, accG.x);            \
    accG.y = fmaf(num.y, rd.y, accG.y);            \
  } while (0)

#define PAIRM(E4v, A5, A6, B5, B6) do {            \
    f2 ea = (E4v) * ((A5) * (B6));                 \
    f2 eb = (E4v) * ((B5) * (A6));                 \
    f2 num = ea - eb;                              \
    f2 den = (ea + 1.0f) * (eb + 1.0f);            \
    f2 rd; rd.x = rcpf(den.x); rd.y = rcpf(den.y); \
    accG.x = fmaf(-num.x, rd.x, accG.x);           \
    accG.y = fmaf(-num.y, rd.y, accG.y);           \
  } while (0)

// pos-3 element G3 (+ variant), M4* at pos 4, pairs at pos 5,6
#define T3P(G3, M4A, M4B, M4C, A5, A6, B5, B6, C5, C6) do { \
    f2 E3 = E2 * (G3);                                      \
    PAIRP(E3 * (M4A), B5, B6, C5, C6);                      \
    PAIRM(E3 * (M4B), A5, A6, C5, C6);                      \
    PAIRP(E3 * (M4C), A5, A6, B5, B6);                      \
  } while (0)

#define T3M(G3, M4A, M4B, M4C, A5, A6, B5, B6, C5, C6) do { \
    f2 E3 = E2 * (G3);                                      \
    PAIRM(E3 * (M4A), B5, B6, C5, C6);                      \
    PAIRP(E3 * (M4B), A5, A6, C5, C6);                      \
    PAIRM(E3 * (M4C), A5, A6, B5, B6);                      \
  } while (0)

// One trio: t2-element Q2J at position 2; remaining 4 elements (rows 3..6).
// TA/TB = T3P/T3M for even trio index, T3M/T3P for odd (folds (-1)^j).
#define TRIO(Q2J, TA, TB, g3a, g3b, g3c, g3d, m4a, m4b, m4c, m4d,       \
             p5a, p6a, p5b, p6b, p5c, p6c, p5d, p6d) do {               \
    f2 E2 = E1 * (Q2J);                                                 \
    TA(g3a, m4b, m4c, m4d, p5b, p6b, p5c, p6c, p5d, p6d);               \
    TB(g3b, m4a, m4c, m4d, p5a, p6a, p5c, p6c, p5d, p6d);               \
    TA(g3c, m4a, m4b, m4d, p5a, p6a, p5b, p6b, p5d, p6d);               \
    TB(g3d, m4a, m4b, m4c, p5a, p6a, p5b, p6b, p5c, p6c);               \
  } while (0)

extern "C" __global__ void __launch_bounds__(512, 4)
antisym_leaf_kernel(const float* __restrict__ x0, const float* __restrict__ x1,
                    const float* __restrict__ W0, const float* __restrict__ b0,
                    const float* __restrict__ V0,
                    const float* __restrict__ W1, const float* __restrict__ b1,
                    const float* __restrict__ V1,
                    float* __restrict__ ws) {
  __shared__ float psh[49 * NH];   // P[i][j][h] = exp(2*G[i][j][h])
  __shared__ float xs[NF];
  __shared__ float red[8];

  const int tid  = threadIdx.x;
  const int bid  = blockIdx.x;          // [0, 512)
  const int leaf = bid >> 8;
  const int half = (bid >> 7) & 1;
  const int b    = bid & 127;

  const float* xL = leaf ? x1 : x0;
  const float* WL = leaf ? W1 : W0;
  const float* bL = leaf ? b1 : b0;
  const float* vL = leaf ? V1 : V0;

  // ---- Phase A: stage x row, build P[i][j][h] = exp(2*x_j . W_i[:,h]) in LDS ----
  if (tid < NF) xs[tid] = xL[b * NF + tid];
  __syncthreads();

  for (int idx = tid; idx < 49 * NH; idx += 512) {
    int h  = idx & (NH - 1);
    int ij = idx >> 7;          // 0..48
    int i  = ij / 7;
    int j  = ij - 7 * i;
    const float* wp = WL + i * ND * NH + h;   // coalesced over h
    const float* xp = xs + j * ND;
    float v = 0.f;
#pragma unroll
    for (int k = 0; k < ND; ++k) v = fmaf(xp[k], wp[k * NH], v);
    psh[idx] = __builtin_amdgcn_exp2f(v * CC);
  }
  __syncthreads();

  // ---- Phase B: enumerate 42 (t0,t1) groups x 60 pairs each ----
  const int lane = tid & 63;
  const int wid  = tid >> 6;            // 0..7
  const int slot = (half << 3) | wid;   // 0..15

  f2 bias2 = ((const f2*)bL)[lane];
  f2 V2    = ((const f2*)vL)[lane];
  f2 Eb;
  Eb.x = __builtin_amdgcn_exp2f(bias2.x * CC);
  Eb.y = __builtin_amdgcn_exp2f(bias2.y * CC);
  f2 acc = {0.f, 0.f};

#pragma unroll 1
  for (int k = 0; k < 3; ++k) {
    int g = slot + (k << 4);            // group id
    if (g >= 42) break;
    int t0 = g / 6;
    int c1 = g - 6 * t0;
    int t1 = c1 + (c1 >= t0 ? 1 : 0);
    float sg1 = ((t0 + c1) & 1) ? -1.f : 1.f;

    int rm = 0x7F & ~((1 << t0) | (1 << t1));
    int r0 = __ffs(rm) - 1; rm &= rm - 1;
    int r1 = __ffs(rm) - 1; rm &= rm - 1;
    int r2 = __ffs(rm) - 1; rm &= rm - 1;
    int r3 = __ffs(rm) - 1; rm &= rm - 1;
    int r4 = __ffs(rm) - 1;

    // 27 ds_read_b64: prefix + rows 2..6 for the 5 remaining elements.
    // Each q value is reused 4-12 times below -> must stay register-resident.
    f2 E1  = Eb * GLD(0, t0) * GLD(1, t1);
    f2 q20 = GLD(2, r0), q21 = GLD(2, r1), q22 = GLD(2, r2), q23 = GLD(2, r3), q24 = GLD(2, r4);
    f2 q30 = GLD(3, r0), q31 = GLD(3, r1), q32 = GLD(3, r2), q33 = GLD(3, r3), q34 = GLD(3, r4);
    f2 q40 = GLD(4, r0), q41 = GLD(4, r1), q42 = GLD(4, r2), q43 = GLD(4, r3), q44 = GLD(4, r4);
    f2 q50 = GLD(5, r0), q51 = GLD(5, r1), q52 = GLD(5, r2), q53 = GLD(5, r3), q54 = GLD(5, r4);
    f2 q60 = GLD(6, r0), q61 = GLD(6, r1), q62 = GLD(6, r2), q63 = GLD(6, r3), q64 = GLD(6, r4);

    f2 accG = {0.f, 0.f};
    // trio j: t2 = r_j, relative sign (-1)^j folded via TA/TB swap
    TRIO(q20, T3P, T3M, q31, q32, q33, q34, q41, q42, q43, q44,
         q51, q61, q52, q62, q53, q63, q54, q64);
    TRIO(q21, T3M, T3P, q30, q32, q33, q34, q40, q42, q43, q44,
         q50, q60, q52, q62, q53, q63, q54, q64);
    TRIO(q22, T3P, T3M, q30, q31, q33, q34, q40, q41, q43, q44,
         q50, q60, q51, q61, q53, q63, q54, q64);
    TRIO(q23, T3M, T3P, q30, q31, q32, q34, q40, q41, q42, q44,
         q50, q60, q51, q61, q52, q62, q54, q64);
    TRIO(q24, T3P, T3M, q30, q31, q32, q33, q40, q41, q42, q43,
         q50, q60, q51, q61, q52, q62, q53, q63);

    acc.x = fmaf(sg1, accG.x, acc.x);
    acc.y = fmaf(sg1, accG.y, acc.y);
  }

  // ---- Reduce: partial psi = sum_h V[h] * acc[h] (factor 2 in finalize) ----
  float part = V2.x * acc.x + V2.y * acc.y;
#pragma unroll
  for (int off = 32; off > 0; off >>= 1) part += __shfl_xor(part, off, 64);
  if (lane == 0) red[wid] = part;
  __syncthreads();
  if (tid == 0) {
    float tot = 0.f;
#pragma unroll
    for (int w = 0; w < 8; ++w) tot += red[w];
    ws[leaf * 256 + half * 128 + b] = tot;
  }
}

extern "C" __global__ void finalize_kernel(const float* __restrict__ ws,
                                           float* __restrict__ out) {
  int t = threadIdx.x;
  if (t < NB) {
    float p0 = 2.0f * (ws[t] + ws[128 + t]);
    float p1 = 2.0f * (ws[256 + t] + ws[384 + t]);
    float s0 = (p0 > 0.f) ? 1.f : ((p0 < 0.f) ? -1.f : 0.f);
    float s1 = (p1 > 0.f) ? 1.f : ((p1 < 0.f) ? -1.f : 0.f);
    out[t]      = s0 * s1;                            // sign
    out[NB + t] = logf(fabsf(p0)) + logf(fabsf(p1));  // logabs
  }
}

extern "C" void kernel_launch(void* const* d_in, const int* in_sizes, int n_in,
                              void* d_out, int out_size, void* d_ws, size_t ws_size,
                              hipStream_t stream) {
  const float* x0 = (const float*)d_in[0];
  const float* x1 = (const float*)d_in[1];
  const float* W0 = (const float*)d_in[2];
  const float* b0 = (const float*)d_in[3];
  const float* V0 = (const float*)d_in[4];
  // d_in[5] = c0: cancels under antisymmetrization (sum of signs == 0)
  const float* W1 = (const float*)d_in[6];
  const float* b1 = (const float*)d_in[7];
  const float* V1 = (const float*)d_in[8];
  // d_in[9] = c1: cancels

  float* ws  = (float*)d_ws;      // 512 floats: psi partials [leaf][half][b]
  float* out = (float*)d_out;     // 256 floats: sign[128], logabs[128]

  antisym_leaf_kernel<<<512, 512, 0, stream>>>(x0, x1, W0, b0, V0, W1, b1, V1, ws);
  finalize_kernel<<<1, NB, 0, stream>>>(ws, out);
}

// Round 7
// 30.383 us; speedup vs baseline: 2.8992x; 1.0051x over previous
//
#include <hip/hip_runtime.h>
#include <math.h>

#define NH 128   // hidden
#define ND 16    // per-particle dim
#define NF 112   // 7*ND
#define NB 128   // batch

#define CC 2.8853900817779268f   // 2*log2(e): exp2(CC*s) = e^{2s}

typedef float f2 __attribute__((ext_vector_type(2)));

__device__ __forceinline__ float rcpf(float x) { return __builtin_amdgcn_rcpf(x); }

#define GLD(i, j) (*(const f2*)&psh[((i) * 7 + (j)) * NH + (lane << 1)])

// One T3: pos3-element G3 under trio prefix E2v; pos4 iterates sorted {p,q,r}
// with relative signs +,-,+; pair (5,6) products P*/M* precomputed.
// Shared denominator: n1/d1 - n2/d2 + n3/d3 = (n1*d23 - n2*d13 + n3*d12)/(d1*d2*d3)
// -> ONE rcp per 3 pairs (6 permutations) per channel.
#define T3P(E2v, G3, M4P, M4Q, M4R, P1, M1, P2, M2, P3, M3) do { \
    f2 E3 = (E2v) * (G3);                                        \
    f2 e4p = E3 * (M4P), e4q = E3 * (M4Q), e4r = E3 * (M4R);     \
    f2 ea1 = e4p * (P1), eb1 = e4p * (M1);                       \
    f2 ea2 = e4q * (P2), eb2 = e4q * (M2);                       \
    f2 ea3 = e4r * (P3), eb3 = e4r * (M3);                       \
    f2 n1 = ea1 - eb1, n2 = ea2 - eb2, n3 = ea3 - eb3;           \
    f2 d1 = (ea1 + 1.0f) * (eb1 + 1.0f);                         \
    f2 d2 = (ea2 + 1.0f) * (eb2 + 1.0f);                         \
    f2 d3 = (ea3 + 1.0f) * (eb3 + 1.0f);                         \
    f2 d23 = d2 * d3, d13 = d1 * d3, d12 = d1 * d2;              \
    f2 N = n1 * d23;                                             \
    N.x = fmaf(-n2.x, d13.x, N.x); N.y = fmaf(-n2.y, d13.y, N.y);\
    N.x = fmaf( n3.x, d12.x, N.x); N.y = fmaf( n3.y, d12.y, N.y);\
    f2 D = d12 * d3;                                             \
    f2 rd; rd.x = rcpf(D.x); rd.y = rcpf(D.y);                   \
    accG.x = fmaf(N.x, rd.x, accG.x);                            \
    accG.y = fmaf(N.y, rd.y, accG.y);                            \
  } while (0)

#define T3M(E2v, G3, M4P, M4Q, M4R, P1, M1, P2, M2, P3, M3) do { \
    f2 E3 = (E2v) * (G3);                                        \
    f2 e4p = E3 * (M4P), e4q = E3 * (M4Q), e4r = E3 * (M4R);     \
    f2 ea1 = e4p * (P1), eb1 = e4p * (M1);                       \
    f2 ea2 = e4q * (P2), eb2 = e4q * (M2);                       \
    f2 ea3 = e4r * (P3), eb3 = e4r * (M3);                       \
    f2 n1 = ea1 - eb1, n2 = ea2 - eb2, n3 = ea3 - eb3;           \
    f2 d1 = (ea1 + 1.0f) * (eb1 + 1.0f);                         \
    f2 d2 = (ea2 + 1.0f) * (eb2 + 1.0f);                         \
    f2 d3 = (ea3 + 1.0f) * (eb3 + 1.0f);                         \
    f2 d23 = d2 * d3, d13 = d1 * d3, d12 = d1 * d2;              \
    f2 N = n1 * d23;                                             \
    N.x = fmaf(-n2.x, d13.x, N.x); N.y = fmaf(-n2.y, d13.y, N.y);\
    N.x = fmaf( n3.x, d12.x, N.x); N.y = fmaf( n3.y, d12.y, N.y);\
    f2 D = d12 * d3;                                             \
    f2 rd; rd.x = rcpf(D.x); rd.y = rcpf(D.y);                   \
    accG.x = fmaf(-N.x, rd.x, accG.x);                           \
    accG.y = fmaf(-N.y, rd.y, accG.y);                           \
  } while (0)

// Trio: t2-element Q2J at pos 2; remaining sorted {a,b,c,d} fill pos 3..6.
// TA/TB = T3P/T3M (even trio) or swapped (odd trio), folding (-1)^trio.
// T3 pair mapping: pos3=a -> pos4 over {b,c,d}, pairs (c,d),(b,d),(b,c); etc.
#define TRIO(Q2J, TA, TB, g3a, g3b, g3c, g3d, m4a, m4b, m4c, m4d,   \
             Pcd, Mcd, Pbd, Mbd, Pbc, Mbc, Pad, Mad, Pac, Mac, Pab, Mab) do { \
    f2 E2 = E1 * (Q2J);                                             \
    TA(E2, g3a, m4b, m4c, m4d, Pcd, Mcd, Pbd, Mbd, Pbc, Mbc);       \
    TB(E2, g3b, m4a, m4c, m4d, Pcd, Mcd, Pad, Mad, Pac, Mac);       \
    TA(E2, g3c, m4a, m4b, m4d, Pbd, Mbd, Pad, Mad, Pab, Mab);       \
    TB(E2, g3d, m4a, m4b, m4c, Pbc, Mbc, Pac, Mac, Pab, Mab);       \
  } while (0)

extern "C" __global__ void __launch_bounds__(512, 4)
antisym_leaf_kernel(const float* __restrict__ x0, const float* __restrict__ x1,
                    const float* __restrict__ W0, const float* __restrict__ b0,
                    const float* __restrict__ V0,
                    const float* __restrict__ W1, const float* __restrict__ b1,
                    const float* __restrict__ V1,
                    float* __restrict__ ws) {
  __shared__ float psh[49 * NH];   // P[i][j][h] = exp(2*G[i][j][h])
  __shared__ float xs[NF];
  __shared__ float red[8];

  const int tid  = threadIdx.x;
  const int bid  = blockIdx.x;          // [0, 512)
  const int leaf = bid >> 8;
  const int half = (bid >> 7) & 1;
  const int b    = bid & 127;

  const float* xL = leaf ? x1 : x0;
  const float* WL = leaf ? W1 : W0;
  const float* bL = leaf ? b1 : b0;
  const float* vL = leaf ? V1 : V0;

  // ---- Phase A: stage x row, build P[i][j][h] = exp(2*x_j . W_i[:,h]) in LDS ----
  if (tid < NF) xs[tid] = xL[b * NF + tid];
  __syncthreads();

  for (int idx = tid; idx < 49 * NH; idx += 512) {
    int h  = idx & (NH - 1);
    int ij = idx >> 7;          // 0..48
    int i  = ij / 7;
    int j  = ij - 7 * i;
    const float* wp = WL + i * ND * NH + h;   // coalesced over h
    const float* xp = xs + j * ND;
    float v = 0.f;
#pragma unroll
    for (int k = 0; k < ND; ++k) v = fmaf(xp[k], wp[k * NH], v);
    psh[idx] = __builtin_amdgcn_exp2f(v * CC);
  }
  __syncthreads();

  // ---- Phase B: 42 (t0,t1) groups x 120 perms each ----
  const int lane = tid & 63;
  const int wid  = tid >> 6;            // 0..7
  const int slot = (half << 3) | wid;   // 0..15

  f2 bias2 = ((const f2*)bL)[lane];
  f2 V2    = ((const f2*)vL)[lane];
  f2 Eb;
  Eb.x = __builtin_amdgcn_exp2f(bias2.x * CC);
  Eb.y = __builtin_amdgcn_exp2f(bias2.y * CC);
  f2 acc = {0.f, 0.f};

#pragma unroll 1
  for (int k = 0; k < 3; ++k) {
    int g = slot + (k << 4);            // group id
    if (g >= 42) break;
    int t0 = g / 6;
    int c1 = g - 6 * t0;
    int t1 = c1 + (c1 >= t0 ? 1 : 0);
    float sg1 = ((t0 + c1) & 1) ? -1.f : 1.f;

    int rm = 0x7F & ~((1 << t0) | (1 << t1));
    int r0 = __ffs(rm) - 1; rm &= rm - 1;
    int r1 = __ffs(rm) - 1; rm &= rm - 1;
    int r2 = __ffs(rm) - 1; rm &= rm - 1;
    int r3 = __ffs(rm) - 1; rm &= rm - 1;
    int r4 = __ffs(rm) - 1;

    // 27 ds_read_b64, one batch per group (values reused 4-12x below)
    f2 E1  = Eb * GLD(0, t0) * GLD(1, t1);
    f2 q20 = GLD(2, r0), q21 = GLD(2, r1), q22 = GLD(2, r2), q23 = GLD(2, r3), q24 = GLD(2, r4);
    f2 g30 = GLD(3, r0), g31 = GLD(3, r1), g32 = GLD(3, r2), g33 = GLD(3, r3), g34 = GLD(3, r4);
    f2 m40 = GLD(4, r0), m41 = GLD(4, r1), m42 = GLD(4, r2), m43 = GLD(4, r3), m44 = GLD(4, r4);
    f2 q50 = GLD(5, r0), q51 = GLD(5, r1), q52 = GLD(5, r2), q53 = GLD(5, r3), q54 = GLD(5, r4);
    f2 q60 = GLD(6, r0), q61 = GLD(6, r1), q62 = GLD(6, r2), q63 = GLD(6, r3), q64 = GLD(6, r4);

    // 20 cross products, each used 6x: PXY = q5X*q6Y (even orient), MXY = q5Y*q6X
    f2 P01 = q50 * q61, M01 = q51 * q60;
    f2 P02 = q50 * q62, M02 = q52 * q60;
    f2 P03 = q50 * q63, M03 = q53 * q60;
    f2 P04 = q50 * q64, M04 = q54 * q60;
    f2 P12 = q51 * q62, M12 = q52 * q61;
    f2 P13 = q51 * q63, M13 = q53 * q61;
    f2 P14 = q51 * q64, M14 = q54 * q61;
    f2 P23 = q52 * q63, M23 = q53 * q62;
    f2 P24 = q52 * q64, M24 = q54 * q62;
    f2 P34 = q53 * q64, M34 = q54 * q63;

    f2 accG = {0.f, 0.f};
    TRIO(q20, T3P, T3M, g31, g32, g33, g34, m41, m42, m43, m44,
         P34, M34, P24, M24, P23, M23, P14, M14, P13, M13, P12, M12);
    TRIO(q21, T3M, T3P, g30, g32, g33, g34, m40, m42, m43, m44,
         P34, M34, P24, M24, P23, M23, P04, M04, P03, M03, P02, M02);
    TRIO(q22, T3P, T3M, g30, g31, g33, g34, m40, m41, m43, m44,
         P34, M34, P14, M14, P13, M13, P04, M04, P03, M03, P01, M01);
    TRIO(q23, T3M, T3P, g30, g31, g32, g34, m40, m41, m42, m44,
         P24, M24, P14, M14, P12, M12, P04, M04, P02, M02, P01, M01);
    TRIO(q24, T3P, T3M, g30, g31, g32, g33, m40, m41, m42, m43,
         P23, M23, P13, M13, P12, M12, P03, M03, P02, M02, P01, M01);

    acc.x = fmaf(sg1, accG.x, acc.x);
    acc.y = fmaf(sg1, accG.y, acc.y);
  }

  // ---- Reduce: partial psi = sum_h V[h] * acc[h] (factor 2 in finalize) ----
  float part = V2.x * acc.x + V2.y * acc.y;
#pragma unroll
  for (int off = 32; off > 0; off >>= 1) part += __shfl_xor(part, off, 64);
  if (lane == 0) red[wid] = part;
  __syncthreads();
  if (tid == 0) {
    float tot = 0.f;
#pragma unroll
    for (int w = 0; w < 8; ++w) tot += red[w];
    ws[leaf * 256 + half * 128 + b] = tot;
  }
}

extern "C" __global__ void finalize_kernel(const float* __restrict__ ws,
                                           float* __restrict__ out) {
  int t = threadIdx.x;
  if (t < NB) {
    float p0 = 2.0f * (ws[t] + ws[128 + t]);
    float p1 = 2.0f * (ws[256 + t] + ws[384 + t]);
    float s0 = (p0 > 0.f) ? 1.f : ((p0 < 0.f) ? -1.f : 0.f);
    float s1 = (p1 > 0.f) ? 1.f : ((p1 < 0.f) ? -1.f : 0.f);
    out[t]      = s0 * s1;                            // sign
    out[NB + t] = logf(fabsf(p0)) + logf(fabsf(p1));  // logabs
  }
}

extern "C" void kernel_launch(void* const* d_in, const int* in_sizes, int n_in,
                              void* d_out, int out_size, void* d_ws, size_t ws_size,
                              hipStream_t stream) {
  const float* x0 = (const float*)d_in[0];
  const float* x1 = (const float*)d_in[1];
  const float* W0 = (const float*)d_in[2];
  const float* b0 = (const float*)d_in[3];
  const float* V0 = (const float*)d_in[4];
  // d_in[5] = c0: cancels under antisymmetrization (sum of signs == 0)
  const float* W1 = (const float*)d_in[6];
  const float* b1 = (const float*)d_in[7];
  const float* V1 = (const float*)d_in[8];
  // d_in[9] = c1: cancels

  float* ws  = (float*)d_ws;      // 512 floats: psi partials [leaf][half][b]
  float* out = (float*)d_out;     // 256 floats: sign[128], logabs[128]

  antisym_leaf_kernel<<<512, 512, 0, stream>>>(x0, x1, W0, b0, V0, W1, b1, V1, ws);
  finalize_kernel<<<1, NB, 0, stream>>>(ws, out);
}